// Round 4
// baseline (343.549 us; speedup 1.0000x reference)
//
#include <hip/hip_runtime.h>
#include <hip/hip_bf16.h>

#define IN_CH 4096
#define OUT_CH 11008

#define BM 128
#define BN 32
#define BK 64
#define KCHUNKS (IN_CH / BK)   // 64
#define NBLOCKS (OUT_CH / BN)  // 344
#define BPAD 72                // B LDS row stride (64 + 8 pad)

typedef short bf16x8 __attribute__((ext_vector_type(8)));
typedef float f32x4 __attribute__((ext_vector_type(4)));

#define GLOBAL_AS __attribute__((address_space(1)))
#define LDS_AS __attribute__((address_space(3)))

__device__ inline unsigned short f2bf(float f) {
    union { __hip_bfloat16 h; unsigned short u; } cv;
    cv.h = __float2bfloat16(f);
    return cv.u;
}

// ---------------------------------------------------------------------------
// Kernel 1 (tiny): x fp32 -> bf16. 16 blocks x 256 thr, 32 float4 iters each.
// ---------------------------------------------------------------------------
__global__ __launch_bounds__(256) void xconv_kernel(
        const float* __restrict__ x, unsigned short* __restrict__ xq) {
    const int tid = threadIdx.x;
    const float4* x4 = (const float4*)x;
    for (int it = 0; it < 32; ++it) {
        const int g = blockIdx.x * 8192 + it * 256 + tid;
        float4 v = x4[g];
        ushort4 o;
        o.x = f2bf(v.x); o.y = f2bf(v.y); o.z = f2bf(v.z); o.w = f2bf(v.w);
        ((ushort4*)xq)[g] = o;
    }
}

// ---------------------------------------------------------------------------
// Kernel 2 (fused): per-block 32-row W slab.
// Phase 1: stream slab fp32, compute s1r[32][64] in LDS (exact LPBQ math).
// Phase 2: full-K MFMA GEMM; B tile dequantized on the fly from an L3-hot
// re-read of the slab (register prefetch overlapped with MFMA). Bias fused.
// ---------------------------------------------------------------------------
__global__ __launch_bounds__(256) void fused_kernel(
        const float* __restrict__ w, const unsigned short* __restrict__ xq,
        const float* __restrict__ bias, float* __restrict__ out) {
    __shared__ float s1r[BN * KCHUNKS];                       // 8 KB
    __shared__ __align__(16) unsigned short ldsA[BM * BK];    // 16 KB
    __shared__ __align__(16) unsigned short ldsB[BN * BPAD];  // 4.5 KB

    const int tid = threadIdx.x;
    const int n0 = blockIdx.x * BN;

    // ================= Phase 1: scales =================
    {
        const int kb = tid >> 2;   // kblock 0..63 (row = it)
        const int q4 = tid & 3;    // quarter of the 64-el kblock (16 el)
        for (int it = 0; it < BN; ++it) {
            const float4* p =
                (const float4*)(w + (size_t)(n0 + it) * IN_CH + kb * 64 + q4 * 16);
            float4 a = p[0], b = p[1], c = p[2], d = p[3];
            float m = fmaxf(
                fmaxf(fmaxf(fmaxf(fabsf(a.x), fabsf(a.y)), fmaxf(fabsf(a.z), fabsf(a.w))),
                      fmaxf(fmaxf(fabsf(b.x), fabsf(b.y)), fmaxf(fabsf(b.z), fabsf(b.w)))),
                fmaxf(fmaxf(fmaxf(fabsf(c.x), fabsf(c.y)), fmaxf(fabsf(c.z), fabsf(c.w))),
                      fmaxf(fmaxf(fabsf(d.x), fabsf(d.y)), fmaxf(fabsf(d.z), fabsf(d.w)))));
            m = fmaxf(m, __shfl_xor(m, 1));
            m = fmaxf(m, __shfl_xor(m, 2));
            if (q4 == 0)
                s1r[it * KCHUNKS + kb] = fmaxf(m * (1.0f / 7.0f), 1e-8f);
        }
        __syncthreads();

        // per-row s2 then s1r in place (8 threads/row, 8 entries each)
        const int row = tid >> 3;
        const int j8 = tid & 7;
        float v[8];
        float m = 0.0f;
        for (int t = 0; t < 8; ++t) {
            v[t] = s1r[row * KCHUNKS + j8 * 8 + t];
            m = fmaxf(m, v[t]);
        }
        m = fmaxf(m, __shfl_xor(m, 1));
        m = fmaxf(m, __shfl_xor(m, 2));
        m = fmaxf(m, __shfl_xor(m, 4));
        const float s2 = fmaxf(m * (1.0f / 15.0f), 1e-8f);
        for (int t = 0; t < 8; ++t) {
            const float s1q = fminf(fmaxf(rintf(v[t] / s2), 0.0f), 15.0f);
            s1r[row * KCHUNKS + j8 * 8 + t] = s1q * s2;
        }
        __syncthreads();
    }

    // ================= Phase 2: GEMM with inline dequant =================
    const int w4 = tid >> 6, l = tid & 63;
    const int r8 = l >> 3, sg = l & 7;        // A staging
    const int brow = tid >> 3, bseg = tid & 7; // B staging: 32 rows x 8 seg
    const int lane15 = l & 15, quad = l >> 4;

    f32x4 acc[2][2] = {};

    const float* wrow = w + (size_t)(n0 + brow) * IN_CH + bseg * 8;
    float4 c0 = *(const float4*)(wrow);
    float4 c1 = *(const float4*)(wrow + 4);

    for (int kc = 0; kc < KCHUNKS; ++kc) {
        // ---- A tile: async global -> LDS ----
        for (int i = 0; i < 4; ++i) {
            const unsigned short* gp =
                xq + (size_t)(i * 32 + w4 * 8 + r8) * IN_CH + kc * 64 + sg * 8;
            LDS_AS unsigned short* lp =
                (LDS_AS unsigned short*)&ldsA[(i * 32 + w4 * 8) * BK];
            __builtin_amdgcn_global_load_lds((const GLOBAL_AS void*)gp,
                                             (LDS_AS void*)lp, 16, 0, 0);
        }

        // ---- B tile: dequant current prefetch regs -> LDS bf16 ----
        const float s1 = s1r[brow * KCHUNKS + kc];
        {
            float fv[8] = {c0.x, c0.y, c0.z, c0.w, c1.x, c1.y, c1.z, c1.w};
            bf16x8 ob;
            for (int t = 0; t < 8; ++t) {
                const float q = fminf(fmaxf(rintf(fv[t] / s1), -8.0f), 7.0f);
                ob[t] = (short)f2bf(q * s1);
            }
            *(bf16x8*)&ldsB[brow * BPAD + bseg * 8] = ob;
        }

        __syncthreads();   // barrier 1: drains A-lds loads, B writes visible

        // ---- W prefetch for kc+1: latency overlaps MFMA ----
        if (kc + 1 < KCHUNKS) {
            c0 = *(const float4*)(wrow + (kc + 1) * 64);
            c1 = *(const float4*)(wrow + (kc + 1) * 64 + 4);
        }

        // ---- MFMA over the 64-deep chunk ----
        for (int kk = 0; kk < 2; ++kk) {
            const int ko = kk * 32 + quad * 8;
            bf16x8 af[2], bfv[2];
            af[0] = *(const bf16x8*)&ldsA[(w4 * 32 + lane15) * BK + ko];
            af[1] = *(const bf16x8*)&ldsA[(w4 * 32 + 16 + lane15) * BK + ko];
            bfv[0] = *(const bf16x8*)&ldsB[lane15 * BPAD + ko];
            bfv[1] = *(const bf16x8*)&ldsB[(16 + lane15) * BPAD + ko];
            for (int i = 0; i < 2; ++i)
                for (int j = 0; j < 2; ++j)
                    acc[i][j] = __builtin_amdgcn_mfma_f32_16x16x32_bf16(
                        af[i], bfv[j], acc[i][j], 0, 0, 0);
        }
        __syncthreads();   // barrier 2: LDS reusable next iter
    }

    // ---- epilogue: bias + store. C/D layout col=lane&15, row=quad*4+reg ----
    const int m_base = w4 * 32 + quad * 4;
    for (int j = 0; j < 2; ++j) {
        const int n = n0 + j * 16 + lane15;
        const float bv = bias[n];
        for (int i = 0; i < 2; ++i) {
            float* cp = out + (size_t)(m_base + i * 16) * OUT_CH + n;
            cp[0 * OUT_CH] = acc[i][j][0] + bv;
            cp[1 * OUT_CH] = acc[i][j][1] + bv;
            cp[2 * OUT_CH] = acc[i][j][2] + bv;
            cp[3 * OUT_CH] = acc[i][j][3] + bv;
        }
    }
}

extern "C" void kernel_launch(void* const* d_in, const int* in_sizes, int n_in,
                              void* d_out, int out_size, void* d_ws, size_t ws_size,
                              hipStream_t stream) {
    const float* x = (const float*)d_in[0];       // (1,128,4096) fp32
    const float* weight = (const float*)d_in[1];  // (11008,4096) fp32
    const float* bias = (const float*)d_in[2];    // (11008,) fp32
    float* out = (float*)d_out;                   // (1,128,11008) fp32

    unsigned short* wsX = (unsigned short*)d_ws;  // 1 MB bf16 x

    xconv_kernel<<<16, 256, 0, stream>>>(x, wsX);
    fused_kernel<<<NBLOCKS, 256, 0, stream>>>(weight, wsX, bias, out);
}

// Round 5
// 293.446 us; speedup vs baseline: 1.1707x; 1.1707x over previous
//
#include <hip/hip_runtime.h>
#include <hip/hip_bf16.h>

#define IN_CH 4096
#define OUT_CH 11008
#define QBLK 64

#define BM 128
#define BN 64
#define BK 64
#define KCHUNKS (IN_CH / BK)            // 64
#define KSPLIT 4
#define SPLIT_CHUNKS (KCHUNKS / KSPLIT) // 16
#define NTILES (OUT_CH / BN)            // 172
#define XCONV_BLOCKS 16
#define BPAD 72                          // B LDS row stride (64 + 8 pad)

typedef short bf16x8 __attribute__((ext_vector_type(8)));
typedef float f32x4 __attribute__((ext_vector_type(4)));
typedef char char16v __attribute__((ext_vector_type(16)));

#define GLOBAL_AS __attribute__((address_space(1)))
#define LDS_AS __attribute__((address_space(3)))

__device__ inline unsigned short f2bf(float f) {
    union { __hip_bfloat16 h; unsigned short u; } cv;
    cv.h = __float2bfloat16(f);
    return cv.u;
}

// ---------------------------------------------------------------------------
// Kernel 1: LPBQ quantize of weight -> int8 w_q + fp32 s1r transposed
// [kblock][row]. Blocks [OUT_CH, OUT_CH+16) convert x -> bf16 with an
// XOR-swizzled granule layout:
//   xq[row][kc*64 + g*8 + t] = bf16(x[row][kc*64 + (g^(row&7))*8 + t])
// so that global_load_lds's rigid lane->LDS mapping yields a bank-conflict-
// free fragment read in the GEMM (granule coset covers all 8 positions).
// ---------------------------------------------------------------------------
__global__ __launch_bounds__(256) void quant_kernel(
        const float* __restrict__ w, const float* __restrict__ x,
        signed char* __restrict__ wq, float* __restrict__ s1rT,
        unsigned short* __restrict__ xq) {
    const int tid = threadIdx.x;

    if (blockIdx.x >= OUT_CH) {
        // ---- x fp32 -> bf16, swizzled. 65536 granules of 8 el. ----
        const int bx = blockIdx.x - OUT_CH;
        for (int it = 0; it < 16; ++it) {
            const int G = it * 4096 + bx * 256 + tid;   // granule id
            const int row = G >> 9;                     // 512 granules/row
            const int gi = G & 511;                     // granule in row
            const int kc = gi >> 3;
            const int gp = gi & 7;
            const int gl = gp ^ (row & 7);              // logical granule
            const float4* src =
                (const float4*)(x + (size_t)row * IN_CH + kc * 64 + gl * 8);
            float4 a = src[0], b = src[1];
            ushort4 o0, o1;
            o0.x = f2bf(a.x); o0.y = f2bf(a.y); o0.z = f2bf(a.z); o0.w = f2bf(a.w);
            o1.x = f2bf(b.x); o1.y = f2bf(b.y); o1.z = f2bf(b.z); o1.w = f2bf(b.w);
            ushort4* dst = (ushort4*)(xq + (size_t)row * IN_CH + gi * 8);
            dst[0] = o0;
            dst[1] = o1;
        }
        return;
    }

    const int row = blockIdx.x;
    const float* wrow = w + (size_t)row * IN_CH;
    signed char* orow = wq + (size_t)row * IN_CH;

    __shared__ float s1_lds[64];   // pass A: s1; after pass B: s1r

    float4 v[4];
    const int lane16 = tid & 15;

    // Pass A: per-64-block max|.| -> s1 (16 lanes per quant-block)
    for (int p = 0; p < 4; ++p) {
        v[p] = ((const float4*)wrow)[p * 256 + tid];
        float m = fmaxf(fmaxf(fabsf(v[p].x), fabsf(v[p].y)),
                        fmaxf(fabsf(v[p].z), fabsf(v[p].w)));
        m = fmaxf(m, __shfl_xor(m, 1));
        m = fmaxf(m, __shfl_xor(m, 2));
        m = fmaxf(m, __shfl_xor(m, 4));
        m = fmaxf(m, __shfl_xor(m, 8));
        if (lane16 == 0)
            s1_lds[p * 16 + (tid >> 4)] = fmaxf(m * (1.0f / 7.0f), 1e-8f);
    }
    __syncthreads();

    // Pass B: s2 = clip(max_b s1 / 15, 1e-8); then s1r = clip(rint(s1/s2))*s2
    if (tid < 64) {
        float s1 = s1_lds[tid];
        float m = s1;
        m = fmaxf(m, __shfl_xor(m, 1));
        m = fmaxf(m, __shfl_xor(m, 2));
        m = fmaxf(m, __shfl_xor(m, 4));
        m = fmaxf(m, __shfl_xor(m, 8));
        m = fmaxf(m, __shfl_xor(m, 16));
        m = fmaxf(m, __shfl_xor(m, 32));
        const float s2 = fmaxf(m * (1.0f / 15.0f), 1e-8f);
        const float s1q = fminf(fmaxf(rintf(s1 / s2), 0.0f), 15.0f);
        const float s1r = s1q * s2;
        s1_lds[tid] = s1r;
        s1rT[(size_t)tid * OUT_CH + row] = s1r;   // transposed scale store
    }
    __syncthreads();

    // Pass C: w_q = clip(rint(w / s1r), -8, 7) stored int8
    for (int p = 0; p < 4; ++p) {
        const float s1r = s1_lds[p * 16 + (tid >> 4)];
        char4 o;
        o.x = (signed char)(int)fminf(fmaxf(rintf(v[p].x / s1r), -8.0f), 7.0f);
        o.y = (signed char)(int)fminf(fmaxf(rintf(v[p].y / s1r), -8.0f), 7.0f);
        o.z = (signed char)(int)fminf(fmaxf(rintf(v[p].z / s1r), -8.0f), 7.0f);
        o.w = (signed char)(int)fminf(fmaxf(rintf(v[p].w / s1r), -8.0f), 7.0f);
        ((char4*)orow)[p * 256 + tid] = o;
    }
}

// ---------------------------------------------------------------------------
// Kernel 2: K-split GEMM with fused int8 -> bf16 dequant of B.
// A staged via global_load_lds w=16 from the XOR-swizzled xq; fragment reads
// un-swizzle with pg = (kk*4+quad)^(row&7) -> 2 lanes/bank (conflict-free).
// B staged via registers into BPAD-padded LDS. part[s] = sum_{split s} A.B^T
// ---------------------------------------------------------------------------
__global__ __launch_bounds__(256) void gemm_kernel(
        const unsigned short* __restrict__ A, const signed char* __restrict__ WQ,
        const float* __restrict__ s1rT, float* __restrict__ part) {
    __shared__ __align__(16) unsigned short ldsA[BM * BK];   // 16 KB
    __shared__ __align__(16) unsigned short ldsB[BN * BPAD]; // 9 KB, padded

    const int tid = threadIdx.x;
    const int w = tid >> 6;
    const int l = tid & 63;
    const int wm = w >> 1;
    const int wn = w & 1;
    const int n0 = blockIdx.x * BN;
    const int kc0 = blockIdx.y * SPLIT_CHUNKS;

    const int r8 = l >> 3;       // A staging: row within 8-row group
    const int sg = l & 7;        // A staging: 16B segment in 128B row

    const int brow = tid >> 2;   // B staging: row 0..63 (4 thr/row)
    const int bcg = tid & 3;     // B staging: 16-el col group

    f32x4 acc[4][2] = {};

    const int lane15 = l & 15;
    const int quad = l >> 4;

    for (int kc = kc0; kc < kc0 + SPLIT_CHUNKS; ++kc) {
        const int k0 = kc * BK;

        // ---- A tile: async global -> LDS (swizzled content) ----
        for (int i = 0; i < 4; ++i) {
            const unsigned short* gp =
                A + (size_t)(i * 32 + w * 8 + r8) * IN_CH + k0 + sg * 8;
            LDS_AS unsigned short* lp =
                (LDS_AS unsigned short*)&ldsA[(i * 32 + w * 8) * BK];
            __builtin_amdgcn_global_load_lds((const GLOBAL_AS void*)gp,
                                             (LDS_AS void*)lp, 16, 0, 0);
        }

        // ---- B tile: int8 load -> dequant -> LDS bf16 (padded rows) ----
        const float s1 = s1rT[(size_t)kc * OUT_CH + n0 + brow];
        char16v bq = *(const char16v*)(WQ + (size_t)(n0 + brow) * IN_CH +
                                       k0 + bcg * 16);
        bf16x8 o0, o1;
        for (int i = 0; i < 8; ++i)
            o0[i] = (short)f2bf((float)bq[i] * s1);
        for (int i = 0; i < 8; ++i)
            o1[i] = (short)f2bf((float)bq[8 + i] * s1);
        *(bf16x8*)&ldsB[brow * BPAD + bcg * 16] = o0;
        *(bf16x8*)&ldsB[brow * BPAD + bcg * 16 + 8] = o1;

        asm volatile("s_waitcnt vmcnt(0)" ::: "memory");
        __syncthreads();

        // ---- MFMA over the 64-deep chunk ----
        for (int kk = 0; kk < 2; ++kk) {
            bf16x8 af[4], bfv[2];
            const int ko = kk * 32 + quad * 8;          // logical k offset
            for (int i = 0; i < 4; ++i) {
                const int row = wm * 64 + i * 16 + lane15;
                const int pg = ((kk * 4 + quad) ^ (row & 7)) * 8;  // physical
                af[i] = *(const bf16x8*)&ldsA[row * BK + pg];
            }
            for (int j = 0; j < 2; ++j)
                bfv[j] = *(const bf16x8*)&ldsB[(wn * 32 + j * 16 + lane15) * BPAD + ko];
            for (int i = 0; i < 4; ++i)
                for (int j = 0; j < 2; ++j)
                    acc[i][j] = __builtin_amdgcn_mfma_f32_16x16x32_bf16(
                        af[i], bfv[j], acc[i][j], 0, 0, 0);
        }
        __syncthreads();
    }

    // ---- epilogue: partial store, C/D layout col=lane&15, row=quad*4+reg ----
    float* pbase = part + (size_t)blockIdx.y * BM * OUT_CH;
    const int m_base = wm * 64 + quad * 4;
    const int n_base = n0 + wn * 32 + lane15;
    for (int j = 0; j < 2; ++j) {
        for (int i = 0; i < 4; ++i) {
            const int m = m_base + i * 16;
            float* cp = pbase + (size_t)m * OUT_CH + n_base + j * 16;
            cp[0 * OUT_CH] = acc[i][j][0];
            cp[1 * OUT_CH] = acc[i][j][1];
            cp[2 * OUT_CH] = acc[i][j][2];
            cp[3 * OUT_CH] = acc[i][j][3];
        }
    }
}

// ---------------------------------------------------------------------------
// Kernel 3: reduce K-split partials + bias. Grid (11, 128) x 256 thr, float4.
// ---------------------------------------------------------------------------
__global__ __launch_bounds__(256) void reduce_kernel(
        const float* __restrict__ part, const float* __restrict__ bias,
        float* __restrict__ out) {
    const int m = blockIdx.y;
    const int x4 = blockIdx.x * 256 + threadIdx.x;
    if (x4 >= OUT_CH / 4) return;
    const size_t off = (size_t)m * OUT_CH + x4 * 4;

    float4 acc = ((const float4*)bias)[x4];
    for (int s = 0; s < KSPLIT; ++s) {
        float4 p = *(const float4*)(part + (size_t)s * BM * OUT_CH + off);
        acc.x += p.x; acc.y += p.y; acc.z += p.z; acc.w += p.w;
    }
    *(float4*)(out + off) = acc;
}

extern "C" void kernel_launch(void* const* d_in, const int* in_sizes, int n_in,
                              void* d_out, int out_size, void* d_ws, size_t ws_size,
                              hipStream_t stream) {
    const float* x = (const float*)d_in[0];       // (1,128,4096) fp32
    const float* weight = (const float*)d_in[1];  // (11008,4096) fp32
    const float* bias = (const float*)d_in[2];    // (11008,) fp32
    float* out = (float*)d_out;                   // (1,128,11008) fp32

    // workspace layout (16B-aligned slices)
    signed char* wsQ = (signed char*)d_ws;                        // 45.1 MB int8 w_q
    unsigned short* wsX = (unsigned short*)(wsQ + (size_t)OUT_CH * IN_CH); // 1 MB bf16 x (swizzled)
    float* wsS = (float*)(wsX + (size_t)BM * IN_CH);              // 2.8 MB s1r^T
    float* wsP = wsS + (size_t)QBLK * OUT_CH;                     // 22.5 MB partials

    quant_kernel<<<OUT_CH + XCONV_BLOCKS, 256, 0, stream>>>(weight, x, wsQ, wsS, wsX);
    gemm_kernel<<<dim3(NTILES, KSPLIT), 256, 0, stream>>>(wsX, wsQ, wsS, wsP);
    reduce_kernel<<<dim3((OUT_CH / 4 + 255) / 256, BM), 256, 0, stream>>>(
        wsP, bias, out);
}